// Round 5
// baseline (9658.053 us; speedup 1.0000x reference)
//
#include <hip/hip_runtime.h>
#include <hip/hip_bf16.h>

// LSTM forward, T=512 B=128 D=1024 H=1024, fp32 in/out, bf16 MFMA compute.
//
// Round 5: tagged h transport — fuse flag and data.
//  - h published as u64 words: hi32 = epoch tag (t+1), lo32 = 2 packed bf16.
//    Consumer's h-load IS the poll (load, check tag==t, rare chunk retry).
//    Removes slot post + slot poll + producer vmcnt drain: one L3 hop/step.
//  - no slots, no grid barrier: synchronization emerges from data tags.
//    2-deep ping-pong is safe: P publishes tag t+2 only after P consumed all
//    tag-t+1 words; each wave publishes t+1 only after its tag-t reads.
//  - chunked staged loads: 4 kk per chunk, 2 chunks in flight (16 x 8B agent
//    loads), per-chunk tag check via __all, rare reload path.
//  - everything else as R4: waves 0-3 = H engine, 4-7 = X engine (gx for
//    t+1 in LDS ping-pong), weights in LDS all 512 steps, tiled h layout.

#define NT 512
#define NB 128
#define ND 1024
#define NH 1024

typedef __attribute__((ext_vector_type(8))) __bf16 bf16x8;
typedef __attribute__((ext_vector_type(4))) float  f32x4;
typedef unsigned long long u64;

__device__ __forceinline__ float sigm(float x) { return 1.0f / (1.0f + __expf(-x)); }
__device__ __forceinline__ float tanh_(float x) {
    x = fminf(15.0f, fmaxf(-15.0f, x));
    float e = __expf(-2.0f * x);
    return (1.0f - e) / (1.0f + e);
}

__device__ __forceinline__ u64 aload(const u64* p) {
    return __hip_atomic_load(p, __ATOMIC_RELAXED, __HIP_MEMORY_SCOPE_AGENT);
}

__global__ void __launch_bounds__(512, 2)
lstm_main(const float* __restrict__ x, const float* __restrict__ w_ih,
          const float* __restrict__ b_ih, const float* __restrict__ w_hh,
          const float* __restrict__ b_hh, float* __restrict__ out,
          u64* __restrict__ h_tag)   // [2][k8 0..127][row 0..127][4] tagged u64
{
    __shared__ uint4  ldsB[8192];          // 128 KiB weights: [k8 0..255][c 0..31]
    __shared__ f32x4  gxbuf[2][4][64][2];  // 16 KiB x-projection ping-pong
    __shared__ float  scr[4][16][33];      // 8.25 KiB gate exchange (H waves)

    const int tid  = threadIdx.x;
    const int lane = tid & 63;
    const int gwid = tid >> 6;        // 0..7
    const int wid  = gwid & 3;        // role-local wave id
    const bool isH = (gwid < 4);
    const int bid  = blockIdx.x;

    const int xcd    = bid & 7;                 // consecutive blocks round-robin XCDs
    const int within = bid >> 3;                // 0..31
    const int mbase  = (within & 1) * 64;       // batch-half
    const int jbase  = xcd * 128 + (within >> 1) * 8;  // 8 h-cols per block

    // ---- one-time: W rows for this block's 8 h-cols x 4 gates -> bf16 -> LDS ----
    for (int idx = tid; idx < 8192; idx += 512) {
        const int c  = idx >> 8;
        const int k8 = idx & 255;
        const int grow = (c >> 3) * NH + jbase + (c & 7);
        const float* src = (k8 < 128) ? (w_ih + (size_t)grow * ND + k8 * 8)
                                      : (w_hh + (size_t)grow * NH + (k8 - 128) * 8);
        const float4 f0 = *(const float4*)src;
        const float4 f1 = *(const float4*)(src + 4);
        bf16x8 v;
        v[0]=(__bf16)f0.x; v[1]=(__bf16)f0.y; v[2]=(__bf16)f0.z; v[3]=(__bf16)f0.w;
        v[4]=(__bf16)f1.x; v[5]=(__bf16)f1.y; v[6]=(__bf16)f1.z; v[7]=(__bf16)f1.w;
        ldsB[k8 * 32 + c] = __builtin_bit_cast(uint4, v);
    }

    const int lrow  = mbase + wid * 16 + (lane & 15);  // A-frag batch row
    const int kslot = lane >> 4;                       // frag k-group
    const int bcol  = lane & 15;                       // B-frag column

    // H-engine cell constants: lane owns (crow, jj2) and (crow, jj2+1)
    const int crow = lane >> 2;
    const int jj2  = (lane & 3) * 2;
    const int gb   = mbase + wid * 16 + crow;
    const int gj   = jbase + jj2;
    float bias[4][2], cst[2] = {0.f, 0.f};
    if (isH) {
        #pragma unroll
        for (int g = 0; g < 4; ++g)
            #pragma unroll
            for (int u = 0; u < 2; ++u)
                bias[g][u] = b_ih[g * NH + gj + u] + b_hh[g * NH + gj + u];
    }

    __syncthreads();   // weights staged

    // x-projection for step tt -> gxbuf[buf] (X waves only)
    #define XPART(tt, buf) do {                                                     \
        f32x4 c0a={0,0,0,0}, c0b={0,0,0,0}, c1a={0,0,0,0}, c1b={0,0,0,0};           \
        const float* xt = x + (size_t)(tt)*NB*ND + (size_t)lrow*ND + kslot*8;       \
        _Pragma("unroll")                                                           \
        for (int kk = 0; kk < 32; ++kk) {                                           \
            const float4 f0 = *(const float4*)(xt + kk * 32);                       \
            const float4 f1 = *(const float4*)(xt + kk * 32 + 4);                   \
            bf16x8 a;                                                               \
            a[0]=(__bf16)f0.x; a[1]=(__bf16)f0.y; a[2]=(__bf16)f0.z; a[3]=(__bf16)f0.w; \
            a[4]=(__bf16)f1.x; a[5]=(__bf16)f1.y; a[6]=(__bf16)f1.z; a[7]=(__bf16)f1.w; \
            const int k8 = kk * 4 + kslot;                                          \
            const bf16x8 b0 = __builtin_bit_cast(bf16x8, ldsB[k8 * 32 + bcol]);     \
            const bf16x8 b1 = __builtin_bit_cast(bf16x8, ldsB[k8 * 32 + 16 + bcol]);\
            if (kk & 1) {                                                           \
                c0b = __builtin_amdgcn_mfma_f32_16x16x32_bf16(a, b0, c0b, 0,0,0);   \
                c1b = __builtin_amdgcn_mfma_f32_16x16x32_bf16(a, b1, c1b, 0,0,0);   \
            } else {                                                                \
                c0a = __builtin_amdgcn_mfma_f32_16x16x32_bf16(a, b0, c0a, 0,0,0);   \
                c1a = __builtin_amdgcn_mfma_f32_16x16x32_bf16(a, b1, c1a, 0,0,0);   \
            }                                                                       \
        }                                                                           \
        gxbuf[buf][wid][lane][0] = c0a + c0b;                                       \
        gxbuf[buf][wid][lane][1] = c1a + c1b;                                       \
    } while (0)

    // ---- tagged h-GEMM chunk machinery (4 kk per chunk) ----
    #define LOADC(S, c) do {                                                        \
        _Pragma("unroll")                                                           \
        for (int i_ = 0; i_ < 4; ++i_) {                                            \
            const int k8_ = ((c) * 4 + i_) * 4 + kslot;                             \
            const u64* hp_ = hbase + ((size_t)k8_ * 128 + lrow) * 4;                \
            S[i_][0] = aload(hp_);     S[i_][1] = aload(hp_ + 1);                   \
            S[i_][2] = aload(hp_ + 2); S[i_][3] = aload(hp_ + 3);                   \
        }                                                                           \
    } while (0)

    #define CHK(S, c) do {                                                          \
        for (;;) {                                                                  \
            unsigned bad_ = 0u;                                                     \
            _Pragma("unroll")                                                       \
            for (int i_ = 0; i_ < 4; ++i_) {                                        \
                bad_ |= ((unsigned)(S[i_][0] >> 32)) ^ want;                        \
                bad_ |= ((unsigned)(S[i_][1] >> 32)) ^ want;                        \
                bad_ |= ((unsigned)(S[i_][2] >> 32)) ^ want;                        \
                bad_ |= ((unsigned)(S[i_][3] >> 32)) ^ want;                        \
            }                                                                       \
            if (__all(bad_ == 0u)) break;                                           \
            __builtin_amdgcn_s_sleep(1);                                            \
            LOADC(S, c);                                                            \
        }                                                                           \
    } while (0)

    #define FMA(S, c) do {                                                          \
        _Pragma("unroll")                                                           \
        for (int i_ = 0; i_ < 4; ++i_) {                                            \
            uint4 q_;                                                               \
            q_.x = (unsigned)S[i_][0]; q_.y = (unsigned)S[i_][1];                   \
            q_.z = (unsigned)S[i_][2]; q_.w = (unsigned)S[i_][3];                   \
            const bf16x8 a_ = __builtin_bit_cast(bf16x8, q_);                       \
            const int k8_ = ((c) * 4 + i_) * 4 + kslot;                             \
            const bf16x8 b0_ = __builtin_bit_cast(bf16x8, ldsB[(128+k8_)*32 + bcol]);\
            const bf16x8 b1_ = __builtin_bit_cast(bf16x8, ldsB[(128+k8_)*32 + 16 + bcol]);\
            if (i_ & 1) {                                                           \
                acc0b = __builtin_amdgcn_mfma_f32_16x16x32_bf16(a_, b0_, acc0b,0,0,0);\
                acc1b = __builtin_amdgcn_mfma_f32_16x16x32_bf16(a_, b1_, acc1b,0,0,0);\
            } else {                                                                \
                acc0  = __builtin_amdgcn_mfma_f32_16x16x32_bf16(a_, b0_, acc0,0,0,0);\
                acc1  = __builtin_amdgcn_mfma_f32_16x16x32_bf16(a_, b1_, acc1,0,0,0);\
            }                                                                       \
        }                                                                           \
    } while (0)

    if (!isH) XPART(0, 0);   // prologue: gx[0]
    __syncthreads();

    for (int t = 0; t < NT; ++t) {
        if (isH) {
            f32x4 acc0 = gxbuf[t & 1][wid][lane][0];
            f32x4 acc1 = gxbuf[t & 1][wid][lane][1];

            if (t) {
                const u64* hbase = h_tag + (size_t)(t & 1) * (128 * 128 * 4);
                const unsigned want = (unsigned)t;
                f32x4 acc0b = {0,0,0,0}, acc1b = {0,0,0,0};
                u64 sA[4][4], sB[4][4];

                LOADC(sA, 0); LOADC(sB, 1);
                CHK(sA, 0); FMA(sA, 0); LOADC(sA, 2);
                CHK(sB, 1); FMA(sB, 1); LOADC(sB, 3);
                CHK(sA, 2); FMA(sA, 2); LOADC(sA, 4);
                CHK(sB, 3); FMA(sB, 3); LOADC(sB, 5);
                CHK(sA, 4); FMA(sA, 4); LOADC(sA, 6);
                CHK(sB, 5); FMA(sB, 5); LOADC(sB, 7);
                CHK(sA, 6); FMA(sA, 6);
                CHK(sB, 7); FMA(sB, 7);

                acc0 += acc0b; acc1 += acc1b;
            }

            // ---- intra-wave gate exchange (C-layout: col=lane&15, row=(lane>>4)*4+r) ----
            #pragma unroll
            for (int r = 0; r < 4; ++r) {
                scr[wid][kslot * 4 + r][bcol]      = acc0[r];
                scr[wid][kslot * 4 + r][bcol + 16] = acc1[r];
            }

            // ---- cell update ----
            float hv[2];
            #pragma unroll
            for (int u = 0; u < 2; ++u) {
                const float iv = sigm (scr[wid][crow][ 0 + jj2 + u] + bias[0][u]);
                const float fv = sigm (scr[wid][crow][ 8 + jj2 + u] + bias[1][u]);
                const float gv = tanh_(scr[wid][crow][16 + jj2 + u] + bias[2][u]);
                const float ov = sigm (scr[wid][crow][24 + jj2 + u] + bias[3][u]);
                const float cc = fv * cst[u] + iv * gv;
                cst[u] = cc;
                hv[u] = ov * tanh_(cc);
            }

            // ---- publish h_t: single tagged u64 (tag t+1), fire-and-forget ----
            if (t + 1 < NT) {
                const unsigned short u0 = __builtin_bit_cast(unsigned short, (__bf16)hv[0]);
                const unsigned short u1 = __builtin_bit_cast(unsigned short, (__bf16)hv[1]);
                const u64 w = ((u64)(unsigned)(t + 1) << 32)
                            | (u64)((unsigned)u0 | ((unsigned)u1 << 16));
                u64* dst = h_tag + (size_t)((t + 1) & 1) * (128 * 128 * 4)
                         + ((size_t)(gj >> 3) * 128 + gb) * 4 + ((gj & 7) >> 1);
                __hip_atomic_store(dst, w, __ATOMIC_RELAXED, __HIP_MEMORY_SCOPE_AGENT);
            }

            // ---- out stores (off critical path) ----
            {
                float2 o; o.x = hv[0]; o.y = hv[1];
                *(float2*)&out[((size_t)t * NB + gb) * NH + gj] = o;
                if (t == NT - 1)
                    *(float2*)&out[(size_t)NT * NB * NH + (size_t)gb * NH + gj] = o; // h_n
            }
        } else {
            if (t + 1 < NT) XPART(t + 1, (t + 1) & 1);   // X engine: next step's gx
        }
        __syncthreads();   // gx handoff (double-buffered)
    }

    // final cell state c_n
    if (isH) {
        float2 cn; cn.x = cst[0]; cn.y = cst[1];
        *(float2*)&out[(size_t)NT * NB * NH + (size_t)NB * NH + (size_t)gb * NH + gj] = cn;
    }
}

extern "C" void kernel_launch(void* const* d_in, const int* in_sizes, int n_in,
                              void* d_out, int out_size, void* d_ws, size_t ws_size,
                              hipStream_t stream)
{
    const float* x    = (const float*)d_in[0];
    const float* w_ih = (const float*)d_in[1];
    const float* b_ih = (const float*)d_in[2];
    const float* w_hh = (const float*)d_in[3];
    const float* b_hh = (const float*)d_in[4];
    float* out = (float*)d_out;

    const size_t htag_bytes = (size_t)2 * 128 * 128 * 4 * sizeof(u64);  // 1 MiB
    if (ws_size < htag_bytes) return;

    u64* h_tag = (u64*)d_ws;

    // zero tags each call (tag 0 is never a wanted epoch; kills stale/garbage tags)
    hipMemsetAsync(h_tag, 0, htag_bytes, stream);

    void* args[] = { (void*)&x, (void*)&w_ih, (void*)&b_ih, (void*)&w_hh,
                     (void*)&b_hh, (void*)&out, (void*)&h_tag };
    hipError_t err = hipLaunchCooperativeKernel((const void*)lstm_main,
                                                dim3(256), dim3(512),
                                                args, 0, stream);
    if (err != hipSuccess) {
        // 256 blocks x 1 block/CU (LDS-bound) are co-resident on 256 CUs
        lstm_main<<<dim3(256), dim3(512), 0, stream>>>(x, w_ih, b_ih, w_hh,
                                                       b_hh, out, h_tag);
    }
}

// Round 8
// 4554.692 us; speedup vs baseline: 2.1205x; 2.1205x over previous
//
#include <hip/hip_runtime.h>
#include <hip/hip_bf16.h>

// LSTM forward, T=512 B=128 D=1024 H=1024, fp32 in/out, bf16 MFMA compute.
//
// Round 8: R6/R7 architecture, ALL-sc1 transport (FAST L2 path deleted).
//  - blocks 0..127 = H engine: group g = bid>>5 owns batch rows 32g..32g+31;
//    block blk = bid&31 owns 32 h-cols (x4 gates). w_hh slice in 128 VGPRs.
//    Per step: poll 32 sc1 epoch flags -> 64KB h A-tile sc1->LDS -> MFMA
//    K=1024 -> cell -> publish h (sc1) -> drain -> flag (sc1).
//  - blocks 128..255 = X engine: gx[t] = x_t*w_ih^T into 4-deep sc1 ring,
//    throttled by consumer epochs; H prefetches gx[t+1] after its flag post.
//  - out stores moved AFTER the flag post (off the inter-block chain).
//  - whole workspace memset each call; epoch flags gate every read.
//  - every spin has a guard (step 1<<17, boot 1<<22) -> no hangs.

#define NT 512
#define NB 128
#define ND 1024
#define NH 1024
#define FSTR 16                 // u32 per flag slot (64 B)
#define GX_BLK 16384            // f32 per (slot, xblk) tile
#define GX_SLOT (32 * GX_BLK)
#define GUARD_STEP (1 << 17)
#define GUARD_BOOT (1 << 22)

typedef __attribute__((ext_vector_type(8))) __bf16 bf16x8;
typedef __attribute__((ext_vector_type(4))) float  f32x4;
typedef __attribute__((ext_vector_type(2))) unsigned long long ullx2;
typedef unsigned long long u64;

__device__ __forceinline__ float sigm(float x) { return 1.0f / (1.0f + __expf(-x)); }
__device__ __forceinline__ float tanh_(float x) {
    x = fminf(15.0f, fmaxf(-15.0f, x));
    float e = __expf(-2.0f * x);
    return (1.0f - e) / (1.0f + e);
}
__device__ __forceinline__ bf16x8 cvt8(const float* p) {
    const float4 f0 = *(const float4*)p;
    const float4 f1 = *(const float4*)(p + 4);
    bf16x8 v;
    v[0] = (__bf16)f0.x; v[1] = (__bf16)f0.y; v[2] = (__bf16)f0.z; v[3] = (__bf16)f0.w;
    v[4] = (__bf16)f1.x; v[5] = (__bf16)f1.y; v[6] = (__bf16)f1.z; v[7] = (__bf16)f1.w;
    return v;
}
__device__ __forceinline__ u64 ald(const u64* p) {
    return __hip_atomic_load(p, __ATOMIC_RELAXED, __HIP_MEMORY_SCOPE_AGENT);
}
__device__ __forceinline__ void ast(u64* p, u64 v) {
    __hip_atomic_store(p, v, __ATOMIC_RELAXED, __HIP_MEMORY_SCOPE_AGENT);
}
__device__ __forceinline__ unsigned aldu(const unsigned* p) {
    return __hip_atomic_load(p, __ATOMIC_RELAXED, __HIP_MEMORY_SCOPE_AGENT);
}
__device__ __forceinline__ void astu(unsigned* p, unsigned v) {
    __hip_atomic_store(p, v, __ATOMIC_RELAXED, __HIP_MEMORY_SCOPE_AGENT);
}

__global__ void __launch_bounds__(512, 2)
lstm_main(const float* __restrict__ x, const float* __restrict__ w_ih,
          const float* __restrict__ b_ih, const float* __restrict__ w_hh,
          const float* __restrict__ b_hh, float* __restrict__ out,
          float* __restrict__ gxr,        // [4][32 xblk][128 wcol][128 row] f32
          unsigned* __restrict__ hbuf,    // [4 grp][2 pp][128 k8][32 row][8 bf16]
          unsigned* __restrict__ l3f,     // [4 grp][32 blk] epoch (L3)
          unsigned* __restrict__ xfl)     // [32 xblk][4 slot] epoch (L3)
{
    __shared__ uint4 ldsA[4096];          // 64 KB: [k8 128][row 32] bf16x8
    __shared__ float scr[8][32][17];      // per-wave gate exchange

    const int tid  = threadIdx.x;
    const int lane = tid & 63;
    const int wid  = tid >> 6;
    const int bid  = blockIdx.x;
    const int c = lane & 15, kslot = lane >> 4;

    if (bid < 128) {
        // ================= H engine (recurrence) =================
        const int g = bid >> 5, blk = bid & 31;

        bf16x8 wreg[32];
        {
            const size_t grow = (size_t)(c >> 2) * NH + blk * 32 + 4 * wid + (c & 3);
            const float* wp = w_hh + grow * NH + kslot * 8;
            #pragma unroll
            for (int kk = 0; kk < 32; ++kk) wreg[kk] = cvt8(wp + kk * 32);
        }
        const int row_l = lane >> 1;
        const int jjo   = (lane & 1) * 2;
        const int j0    = blk * 32 + 4 * wid + jjo;
        float bias[4][2];
        #pragma unroll
        for (int gg = 0; gg < 4; ++gg)
            #pragma unroll
            for (int u = 0; u < 2; ++u)
                bias[gg][u] = b_ih[gg * NH + j0 + u] + b_hh[gg * NH + j0 + u];
        float cst[2] = {0.f, 0.f};

        unsigned* postl3 = l3f + ((size_t)g * 32 + blk) * FSTR;

        f32x4 gxc0, gxc1;
        #define GXLOAD(sl) do {                                                      \
            const u64* gp_ = (const u64*)(const void*)gxr                            \
                + ((((size_t)(sl)) * 32 + blk) * GX_BLK                              \
                   + (size_t)(wid * 16 + c) * 128 + 32 * g + kslot * 4) / 2;         \
            const u64 q0_ = ald(gp_), q1_ = ald(gp_ + 1);                            \
            const u64 q2_ = ald(gp_ + 8), q3_ = ald(gp_ + 9);                        \
            ullx2 t0_, t1_;                                                          \
            t0_[0] = q0_; t0_[1] = q1_; t1_[0] = q2_; t1_[1] = q3_;                  \
            gxc0 = __builtin_bit_cast(f32x4, t0_);                                   \
            gxc1 = __builtin_bit_cast(f32x4, t1_);                                   \
        } while (0)

        {   // prologue: wait for gx[0]
            const unsigned* xfp0 = xfl + ((size_t)blk * 4 + 0) * FSTR;
            int gu = 0;
            while (aldu(xfp0) < 1u) {
                __builtin_amdgcn_s_sleep(8);
                if (++gu > GUARD_BOOT) break;
            }
            GXLOAD(0);
        }

        for (int t = 0; t < NT; ++t) {
            if (t) {
                if (tid < 32) {   // poll my group's 32 producer epochs (sc1)
                    const unsigned* f = l3f + ((size_t)g * 32 + tid) * FSTR;
                    int gu = 0;
                    while (aldu(f) < (unsigned)t) {
                        __builtin_amdgcn_s_sleep(1);
                        if (++gu > GUARD_STEP) break;
                    }
                }
                __syncthreads();
                // A-fill: 64 KB h_{t-1} tile, sc1 (L3) -> LDS
                const u64* s8 = (const u64*)(const void*)
                    (hbuf + ((size_t)g * 2 + ((t + 1) & 1)) * 16384);
                #pragma unroll
                for (int i = 0; i < 8; ++i) {
                    const size_t q = (size_t)(i * 512 + tid) * 2;
                    ullx2 tq; tq[0] = ald(s8 + q); tq[1] = ald(s8 + q + 1);
                    ldsA[i * 512 + tid] = __builtin_bit_cast(uint4, tq);
                }
            }
            // early epoch sample for gx[t+1]
            const unsigned* xfp = xfl + ((size_t)blk * 4 + ((t + 1) & 3)) * FSTR;
            unsigned xfNext = 0xffffffffu;
            if (t + 1 < NT) xfNext = aldu(xfp);
            __syncthreads();

            f32x4 acc0, acc1;
            if (t) {
                f32x4 a0a = gxc0, a1a = gxc1;
                f32x4 a0b = {0,0,0,0}, a1b = {0,0,0,0};
                #pragma unroll
                for (int kk = 0; kk < 32; ++kk) {
                    const bf16x8 a0 = __builtin_bit_cast(bf16x8, ldsA[(kk*4 + kslot)*32 + c]);
                    const bf16x8 a1 = __builtin_bit_cast(bf16x8, ldsA[(kk*4 + kslot)*32 + 16 + c]);
                    if (kk & 1) {
                        a0b = __builtin_amdgcn_mfma_f32_16x16x32_bf16(a0, wreg[kk], a0b, 0,0,0);
                        a1b = __builtin_amdgcn_mfma_f32_16x16x32_bf16(a1, wreg[kk], a1b, 0,0,0);
                    } else {
                        a0a = __builtin_amdgcn_mfma_f32_16x16x32_bf16(a0, wreg[kk], a0a, 0,0,0);
                        a1a = __builtin_amdgcn_mfma_f32_16x16x32_bf16(a1, wreg[kk], a1a, 0,0,0);
                    }
                }
                acc0 = a0a + a0b; acc1 = a1a + a1b;
            } else {
                acc0 = gxc0; acc1 = gxc1;
            }

            // intra-wave gate exchange (C-layout: col=lane&15, row=(lane>>4)*4+r)
            #pragma unroll
            for (int r = 0; r < 4; ++r) {
                scr[wid][kslot * 4 + r][c]      = acc0[r];
                scr[wid][16 + kslot * 4 + r][c] = acc1[r];
            }
            // cell update: lane finishes cells (row_l, j0) and (row_l, j0+1)
            float hv[2];
            #pragma unroll
            for (int u = 0; u < 2; ++u) {
                const float iv = sigm (scr[wid][row_l][ 0 + jjo + u] + bias[0][u]);
                const float fv = sigm (scr[wid][row_l][ 4 + jjo + u] + bias[1][u]);
                const float gv = tanh_(scr[wid][row_l][ 8 + jjo + u] + bias[2][u]);
                const float ov = sigm (scr[wid][row_l][12 + jjo + u] + bias[3][u]);
                const float cc = fv * cst[u] + iv * gv;
                cst[u] = cc;
                hv[u] = ov * tanh_(cc);
            }

            // publish h_t (tiled bf16, sc1) -> drain -> flag
            {
                const unsigned short u0 = __builtin_bit_cast(unsigned short, (__bf16)hv[0]);
                const unsigned short u1 = __builtin_bit_cast(unsigned short, (__bf16)hv[1]);
                const unsigned pack = (unsigned)u0 | ((unsigned)u1 << 16);
                const size_t hidx = ((size_t)g * 2 + (t & 1)) * 16384
                                  + ((size_t)(j0 >> 3) * 32 + row_l) * 4 + ((j0 & 7) >> 1);
                astu(&hbuf[hidx], pack);
            }
            __syncthreads();   // vmcnt(0): h stores at L3 before the flag
            if (tid == 0) astu(postl3, (unsigned)(t + 1));

            // off-critical-path out stores (after flag post)
            {
                float2 o; o.x = hv[0]; o.y = hv[1];
                *(float2*)&out[((size_t)t * NB + 32 * g + row_l) * NH + j0] = o;
                if (t == NT - 1)
                    *(float2*)&out[(size_t)NT * NB * NH + ((size_t)32 * g + row_l) * NH + j0] = o;
            }
            // prefetch gx[t+1]
            if (t + 1 < NT) {
                int gu = 0;
                while (xfNext < (unsigned)(t + 2)) {
                    __builtin_amdgcn_s_sleep(1);
                    xfNext = aldu(xfp);
                    if (++gu > GUARD_STEP) break;
                }
                GXLOAD((t + 1) & 3);
            }
        }
        {   // c_n
            float2 cn; cn.x = cst[0]; cn.y = cst[1];
            *(float2*)&out[(size_t)NT * NB * NH + (size_t)NB * NH
                           + ((size_t)32 * g + row_l) * NH + j0] = cn;
        }
    } else {
        // ================= X engine (gx producer, runs ahead) =================
        const int e = (bid - 128) >> 5, r = bid & 31;

        bf16x8 wreg[32];
        {
            const size_t grow = (size_t)(c >> 2) * NH + r * 32 + 4 * wid + (c & 3);
            const float* wp = w_ih + grow * ND + kslot * 8;
            #pragma unroll
            for (int kk = 0; kk < 32; ++kk) wreg[kk] = cvt8(wp + kk * 32);
        }
        const int xrow = tid >> 4, seg = tid & 15;

        for (int tt = e; tt < NT; tt += 4) {
            if (tt >= 4) {
                // throttle: all 4 consumer groups must have finished step tt-4
                const unsigned* hp = l3f + ((size_t)(lane & 3) * 32 + r) * FSTR;
                int gu = 0;
                while (aldu(hp) < (unsigned)(tt - 3)) {
                    __builtin_amdgcn_s_sleep(4);
                    if (++gu > GUARD_STEP) break;
                }
            }
            __syncthreads();

            f32x4 xa0={0,0,0,0}, xa1={0,0,0,0}, xa2={0,0,0,0}, xa3={0,0,0,0};
            f32x4 xa4={0,0,0,0}, xa5={0,0,0,0}, xa6={0,0,0,0}, xa7={0,0,0,0};

            #define XCHUNK(m, A, B) {                                                \
                const float* xs = x + ((size_t)tt * NB + 32 * (m) + xrow) * ND       \
                                    + seg * 64;                                      \
                _Pragma("unroll")                                                    \
                for (int i2 = 0; i2 < 8; ++i2)                                       \
                    ldsA[(seg * 8 + i2) * 32 + xrow] =                               \
                        __builtin_bit_cast(uint4, cvt8(xs + i2 * 8));                \
                __syncthreads();                                                     \
                _Pragma("unroll")                                                    \
                for (int kk = 0; kk < 32; ++kk) {                                    \
                    const bf16x8 a0 = __builtin_bit_cast(bf16x8,                     \
                        ldsA[(kk*4 + kslot)*32 + c]);                                \
                    const bf16x8 a1 = __builtin_bit_cast(bf16x8,                     \
                        ldsA[(kk*4 + kslot)*32 + 16 + c]);                           \
                    A = __builtin_amdgcn_mfma_f32_16x16x32_bf16(a0, wreg[kk], A, 0,0,0);\
                    B = __builtin_amdgcn_mfma_f32_16x16x32_bf16(a1, wreg[kk], B, 0,0,0);\
                }                                                                    \
                __syncthreads(); }

            XCHUNK(0, xa0, xa1)
            XCHUNK(1, xa2, xa3)
            XCHUNK(2, xa4, xa5)
            XCHUNK(3, xa6, xa7)

            {   // store gx[tt] slot (sc1 -> L3)
                u64* gp = (u64*)(void*)gxr
                    + (((size_t)(tt & 3) * 32 + r) * GX_BLK
                       + (size_t)(wid * 16 + c) * 128 + kslot * 4) / 2;
                #define XSTORE(mt, A) {                                              \
                    const ullx2 q_ = __builtin_bit_cast(ullx2, A);                   \
                    ast(gp + (mt) * 8, q_[0]); ast(gp + (mt) * 8 + 1, q_[1]); }
                XSTORE(0, xa0) XSTORE(1, xa1) XSTORE(2, xa2) XSTORE(3, xa3)
                XSTORE(4, xa4) XSTORE(5, xa5) XSTORE(6, xa6) XSTORE(7, xa7)
            }
            __syncthreads();   // drain vmcnt: slot data at L3 before the flag
            if (tid == 0)
                astu(xfl + ((size_t)r * 4 + (tt & 3)) * FSTR, (unsigned)(tt + 1));
        }
    }
}

extern "C" void kernel_launch(void* const* d_in, const int* in_sizes, int n_in,
                              void* d_out, int out_size, void* d_ws, size_t ws_size,
                              hipStream_t stream)
{
    const float* x    = (const float*)d_in[0];
    const float* w_ih = (const float*)d_in[1];
    const float* b_ih = (const float*)d_in[2];
    const float* w_hh = (const float*)d_in[3];
    const float* b_hh = (const float*)d_in[4];
    float* out = (float*)d_out;

    const size_t gx_bytes = (size_t)4 * GX_SLOT * sizeof(float);      // 8 MB
    const size_t hb_bytes = (size_t)4 * 2 * 16384 * sizeof(unsigned); // 512 KB
    const size_t fl_bytes = (size_t)128 * FSTR * sizeof(unsigned);    // 8 KB each
    const size_t total    = gx_bytes + hb_bytes + 2 * fl_bytes;
    if (ws_size < total) return;

    char* p = (char*)d_ws;
    float*    gxr  = (float*)p;      p += gx_bytes;
    unsigned* hbuf = (unsigned*)p;   p += hb_bytes;
    unsigned* l3f  = (unsigned*)p;   p += fl_bytes;
    unsigned* xfl  = (unsigned*)p;

    // zero EVERYTHING each call: epochs restart at 0; no stale/poison data
    hipMemsetAsync(d_ws, 0, total, stream);

    void* args[] = { (void*)&x, (void*)&w_ih, (void*)&b_ih, (void*)&w_hh,
                     (void*)&b_hh, (void*)&out, (void*)&gxr, (void*)&hbuf,
                     (void*)&l3f, (void*)&xfl };
    hipError_t err = hipLaunchCooperativeKernel((const void*)lstm_main,
                                                dim3(256), dim3(512),
                                                args, 0, stream);
    if (err != hipSuccess) {
        // LDS (~83 KB) forces 1 block/CU; 256 blocks co-reside on 256 CUs
        lstm_main<<<dim3(256), dim3(512), 0, stream>>>(x, w_ih, b_ih, w_hh, b_hh,
                                                       out, gxr, hbuf, l3f, xfl);
    }
}

// Round 9
// 4486.179 us; speedup vs baseline: 2.1528x; 1.0153x over previous
//
#include <hip/hip_runtime.h>
#include <hip/hip_bf16.h>

// LSTM forward, T=512 B=128 D=1024 H=1024, fp32 in/out, bf16 MFMA compute.
//
// Round 9: R8 (all-sc1 transport, PASSED) + one-RTT staged A-fill.
//  - h A-fill: issue ALL 16 sc1 u64 loads into registers, then 8
//    ds_write_b128 (first write waits vmcnt(14), not vmcnt(0) per pair).
//    Collapses ~8 serialized L3 round trips to ~1.
//  - X engine XCHUNK staging likewise (issue 16 float4 loads, then write).
//  - protocol, partitioning, flags, guards: identical to R8.

#define NT 512
#define NB 128
#define ND 1024
#define NH 1024
#define FSTR 16                 // u32 per flag slot (64 B)
#define GX_BLK 16384            // f32 per (slot, xblk) tile
#define GX_SLOT (32 * GX_BLK)
#define GUARD_STEP (1 << 17)
#define GUARD_BOOT (1 << 22)

typedef __attribute__((ext_vector_type(8))) __bf16 bf16x8;
typedef __attribute__((ext_vector_type(4))) float  f32x4;
typedef __attribute__((ext_vector_type(2))) unsigned long long ullx2;
typedef unsigned long long u64;

__device__ __forceinline__ float sigm(float x) { return 1.0f / (1.0f + __expf(-x)); }
__device__ __forceinline__ float tanh_(float x) {
    x = fminf(15.0f, fmaxf(-15.0f, x));
    float e = __expf(-2.0f * x);
    return (1.0f - e) / (1.0f + e);
}
__device__ __forceinline__ bf16x8 cvt8v(float4 f0, float4 f1) {
    bf16x8 v;
    v[0] = (__bf16)f0.x; v[1] = (__bf16)f0.y; v[2] = (__bf16)f0.z; v[3] = (__bf16)f0.w;
    v[4] = (__bf16)f1.x; v[5] = (__bf16)f1.y; v[6] = (__bf16)f1.z; v[7] = (__bf16)f1.w;
    return v;
}
__device__ __forceinline__ bf16x8 cvt8(const float* p) {
    return cvt8v(*(const float4*)p, *(const float4*)(p + 4));
}
__device__ __forceinline__ u64 ald(const u64* p) {
    return __hip_atomic_load(p, __ATOMIC_RELAXED, __HIP_MEMORY_SCOPE_AGENT);
}
__device__ __forceinline__ void ast(u64* p, u64 v) {
    __hip_atomic_store(p, v, __ATOMIC_RELAXED, __HIP_MEMORY_SCOPE_AGENT);
}
__device__ __forceinline__ unsigned aldu(const unsigned* p) {
    return __hip_atomic_load(p, __ATOMIC_RELAXED, __HIP_MEMORY_SCOPE_AGENT);
}
__device__ __forceinline__ void astu(unsigned* p, unsigned v) {
    __hip_atomic_store(p, v, __ATOMIC_RELAXED, __HIP_MEMORY_SCOPE_AGENT);
}

__global__ void __launch_bounds__(512, 2)
lstm_main(const float* __restrict__ x, const float* __restrict__ w_ih,
          const float* __restrict__ b_ih, const float* __restrict__ w_hh,
          const float* __restrict__ b_hh, float* __restrict__ out,
          float* __restrict__ gxr,        // [4][32 xblk][128 wcol][128 row] f32
          unsigned* __restrict__ hbuf,    // [4 grp][2 pp][128 k8][32 row][8 bf16]
          unsigned* __restrict__ l3f,     // [4 grp][32 blk] epoch (L3)
          unsigned* __restrict__ xfl)     // [32 xblk][4 slot] epoch (L3)
{
    __shared__ uint4 ldsA[4096];          // 64 KB: [k8 128][row 32] bf16x8
    __shared__ float scr[8][32][17];      // per-wave gate exchange

    const int tid  = threadIdx.x;
    const int lane = tid & 63;
    const int wid  = tid >> 6;
    const int bid  = blockIdx.x;
    const int c = lane & 15, kslot = lane >> 4;

    if (bid < 128) {
        // ================= H engine (recurrence) =================
        const int g = bid >> 5, blk = bid & 31;

        bf16x8 wreg[32];
        {
            const size_t grow = (size_t)(c >> 2) * NH + blk * 32 + 4 * wid + (c & 3);
            const float* wp = w_hh + grow * NH + kslot * 8;
            #pragma unroll
            for (int kk = 0; kk < 32; ++kk) wreg[kk] = cvt8(wp + kk * 32);
        }
        const int row_l = lane >> 1;
        const int jjo   = (lane & 1) * 2;
        const int j0    = blk * 32 + 4 * wid + jjo;
        float bias[4][2];
        #pragma unroll
        for (int gg = 0; gg < 4; ++gg)
            #pragma unroll
            for (int u = 0; u < 2; ++u)
                bias[gg][u] = b_ih[gg * NH + j0 + u] + b_hh[gg * NH + j0 + u];
        float cst[2] = {0.f, 0.f};

        unsigned* postl3 = l3f + ((size_t)g * 32 + blk) * FSTR;

        f32x4 gxc0, gxc1;
        #define GXLOAD(sl) do {                                                      \
            const u64* gp_ = (const u64*)(const void*)gxr                            \
                + ((((size_t)(sl)) * 32 + blk) * GX_BLK                              \
                   + (size_t)(wid * 16 + c) * 128 + 32 * g + kslot * 4) / 2;         \
            const u64 q0_ = ald(gp_), q1_ = ald(gp_ + 1);                            \
            const u64 q2_ = ald(gp_ + 8), q3_ = ald(gp_ + 9);                        \
            ullx2 t0_, t1_;                                                          \
            t0_[0] = q0_; t0_[1] = q1_; t1_[0] = q2_; t1_[1] = q3_;                  \
            gxc0 = __builtin_bit_cast(f32x4, t0_);                                   \
            gxc1 = __builtin_bit_cast(f32x4, t1_);                                   \
        } while (0)

        {   // prologue: wait for gx[0]
            const unsigned* xfp0 = xfl + ((size_t)blk * 4 + 0) * FSTR;
            int gu = 0;
            while (aldu(xfp0) < 1u) {
                __builtin_amdgcn_s_sleep(8);
                if (++gu > GUARD_BOOT) break;
            }
            GXLOAD(0);
        }

        for (int t = 0; t < NT; ++t) {
            if (t) {
                if (tid < 32) {   // poll my group's 32 producer epochs (sc1)
                    const unsigned* f = l3f + ((size_t)g * 32 + tid) * FSTR;
                    int gu = 0;
                    while (aldu(f) < (unsigned)t) {
                        __builtin_amdgcn_s_sleep(1);
                        if (++gu > GUARD_STEP) break;
                    }
                }
                __syncthreads();
                // A-fill: 64 KB h_{t-1} tile, sc1 (L3) -> regs (ALL loads in
                // flight) -> LDS. One L3 round trip instead of eight.
                const u64* s8 = (const u64*)(const void*)
                    (hbuf + ((size_t)g * 2 + ((t + 1) & 1)) * 16384);
                u64 st[16];
                #pragma unroll
                for (int i = 0; i < 8; ++i) {
                    const size_t q = (size_t)(i * 512 + tid) * 2;
                    st[2 * i]     = ald(s8 + q);
                    st[2 * i + 1] = ald(s8 + q + 1);
                }
                #pragma unroll
                for (int i = 0; i < 8; ++i) {
                    ullx2 tq; tq[0] = st[2 * i]; tq[1] = st[2 * i + 1];
                    ldsA[i * 512 + tid] = __builtin_bit_cast(uint4, tq);
                }
            }
            // early epoch sample for gx[t+1]
            const unsigned* xfp = xfl + ((size_t)blk * 4 + ((t + 1) & 3)) * FSTR;
            unsigned xfNext = 0xffffffffu;
            if (t + 1 < NT) xfNext = aldu(xfp);
            __syncthreads();

            f32x4 acc0, acc1;
            if (t) {
                f32x4 a0a = gxc0, a1a = gxc1;
                f32x4 a0b = {0,0,0,0}, a1b = {0,0,0,0};
                #pragma unroll
                for (int kk = 0; kk < 32; ++kk) {
                    const bf16x8 a0 = __builtin_bit_cast(bf16x8, ldsA[(kk*4 + kslot)*32 + c]);
                    const bf16x8 a1 = __builtin_bit_cast(bf16x8, ldsA[(kk*4 + kslot)*32 + 16 + c]);
                    if (kk & 1) {
                        a0b = __builtin_amdgcn_mfma_f32_16x16x32_bf16(a0, wreg[kk], a0b, 0,0,0);
                        a1b = __builtin_amdgcn_mfma_f32_16x16x32_bf16(a1, wreg[kk], a1b, 0,0,0);
                    } else {
                        a0a = __builtin_amdgcn_mfma_f32_16x16x32_bf16(a0, wreg[kk], a0a, 0,0,0);
                        a1a = __builtin_amdgcn_mfma_f32_16x16x32_bf16(a1, wreg[kk], a1a, 0,0,0);
                    }
                }
                acc0 = a0a + a0b; acc1 = a1a + a1b;
            } else {
                acc0 = gxc0; acc1 = gxc1;
            }

            // intra-wave gate exchange (C-layout: col=lane&15, row=(lane>>4)*4+r)
            #pragma unroll
            for (int r = 0; r < 4; ++r) {
                scr[wid][kslot * 4 + r][c]      = acc0[r];
                scr[wid][16 + kslot * 4 + r][c] = acc1[r];
            }
            // cell update: lane finishes cells (row_l, j0) and (row_l, j0+1)
            float hv[2];
            #pragma unroll
            for (int u = 0; u < 2; ++u) {
                const float iv = sigm (scr[wid][row_l][ 0 + jjo + u] + bias[0][u]);
                const float fv = sigm (scr[wid][row_l][ 4 + jjo + u] + bias[1][u]);
                const float gv = tanh_(scr[wid][row_l][ 8 + jjo + u] + bias[2][u]);
                const float ov = sigm (scr[wid][row_l][12 + jjo + u] + bias[3][u]);
                const float cc = fv * cst[u] + iv * gv;
                cst[u] = cc;
                hv[u] = ov * tanh_(cc);
            }

            // publish h_t (tiled bf16, sc1) -> drain -> flag
            {
                const unsigned short u0 = __builtin_bit_cast(unsigned short, (__bf16)hv[0]);
                const unsigned short u1 = __builtin_bit_cast(unsigned short, (__bf16)hv[1]);
                const unsigned pack = (unsigned)u0 | ((unsigned)u1 << 16);
                const size_t hidx = ((size_t)g * 2 + (t & 1)) * 16384
                                  + ((size_t)(j0 >> 3) * 32 + row_l) * 4 + ((j0 & 7) >> 1);
                astu(&hbuf[hidx], pack);
            }
            __syncthreads();   // vmcnt(0): h stores at L3 before the flag
            if (tid == 0) astu(postl3, (unsigned)(t + 1));

            // off-critical-path out stores (after flag post)
            {
                float2 o; o.x = hv[0]; o.y = hv[1];
                *(float2*)&out[((size_t)t * NB + 32 * g + row_l) * NH + j0] = o;
                if (t == NT - 1)
                    *(float2*)&out[(size_t)NT * NB * NH + ((size_t)32 * g + row_l) * NH + j0] = o;
            }
            // prefetch gx[t+1]
            if (t + 1 < NT) {
                int gu = 0;
                while (xfNext < (unsigned)(t + 2)) {
                    __builtin_amdgcn_s_sleep(1);
                    xfNext = aldu(xfp);
                    if (++gu > GUARD_STEP) break;
                }
                GXLOAD((t + 1) & 3);
            }
        }
        {   // c_n
            float2 cn; cn.x = cst[0]; cn.y = cst[1];
            *(float2*)&out[(size_t)NT * NB * NH + (size_t)NB * NH
                           + ((size_t)32 * g + row_l) * NH + j0] = cn;
        }
    } else {
        // ================= X engine (gx producer, runs ahead) =================
        const int e = (bid - 128) >> 5, r = bid & 31;

        bf16x8 wreg[32];
        {
            const size_t grow = (size_t)(c >> 2) * NH + r * 32 + 4 * wid + (c & 3);
            const float* wp = w_ih + grow * ND + kslot * 8;
            #pragma unroll
            for (int kk = 0; kk < 32; ++kk) wreg[kk] = cvt8(wp + kk * 32);
        }
        const int xrow = tid >> 4, seg = tid & 15;

        for (int tt = e; tt < NT; tt += 4) {
            if (tt >= 4) {
                // throttle: all 4 consumer groups must have finished step tt-4
                const unsigned* hp = l3f + ((size_t)(lane & 3) * 32 + r) * FSTR;
                int gu = 0;
                while (aldu(hp) < (unsigned)(tt - 3)) {
                    __builtin_amdgcn_s_sleep(4);
                    if (++gu > GUARD_STEP) break;
                }
            }
            __syncthreads();

            f32x4 xa0={0,0,0,0}, xa1={0,0,0,0}, xa2={0,0,0,0}, xa3={0,0,0,0};
            f32x4 xa4={0,0,0,0}, xa5={0,0,0,0}, xa6={0,0,0,0}, xa7={0,0,0,0};

            // staged x-chunk: issue all 16 float4 loads, then convert+write
            #define XCHUNK(m, A, B) {                                                \
                const float* xs = x + ((size_t)tt * NB + 32 * (m) + xrow) * ND       \
                                    + seg * 64;                                      \
                float4 xf[16];                                                       \
                _Pragma("unroll")                                                    \
                for (int i2 = 0; i2 < 8; ++i2) {                                     \
                    xf[2 * i2]     = *(const float4*)(xs + i2 * 8);                  \
                    xf[2 * i2 + 1] = *(const float4*)(xs + i2 * 8 + 4);              \
                }                                                                    \
                _Pragma("unroll")                                                    \
                for (int i2 = 0; i2 < 8; ++i2)                                       \
                    ldsA[(seg * 8 + i2) * 32 + xrow] =                               \
                        __builtin_bit_cast(uint4, cvt8v(xf[2*i2], xf[2*i2+1]));      \
                __syncthreads();                                                     \
                _Pragma("unroll")                                                    \
                for (int kk = 0; kk < 32; ++kk) {                                    \
                    const bf16x8 a0 = __builtin_bit_cast(bf16x8,                     \
                        ldsA[(kk*4 + kslot)*32 + c]);                                \
                    const bf16x8 a1 = __builtin_bit_cast(bf16x8,                     \
                        ldsA[(kk*4 + kslot)*32 + 16 + c]);                           \
                    A = __builtin_amdgcn_mfma_f32_16x16x32_bf16(a0, wreg[kk], A, 0,0,0);\
                    B = __builtin_amdgcn_mfma_f32_16x16x32_bf16(a1, wreg[kk], B, 0,0,0);\
                }                                                                    \
                __syncthreads(); }

            XCHUNK(0, xa0, xa1)
            XCHUNK(1, xa2, xa3)
            XCHUNK(2, xa4, xa5)
            XCHUNK(3, xa6, xa7)

            {   // store gx[tt] slot (sc1 -> L3)
                u64* gp = (u64*)(void*)gxr
                    + (((size_t)(tt & 3) * 32 + r) * GX_BLK
                       + (size_t)(wid * 16 + c) * 128 + kslot * 4) / 2;
                #define XSTORE(mt, A) {                                              \
                    const ullx2 q_ = __builtin_bit_cast(ullx2, A);                   \
                    ast(gp + (mt) * 8, q_[0]); ast(gp + (mt) * 8 + 1, q_[1]); }
                XSTORE(0, xa0) XSTORE(1, xa1) XSTORE(2, xa2) XSTORE(3, xa3)
                XSTORE(4, xa4) XSTORE(5, xa5) XSTORE(6, xa6) XSTORE(7, xa7)
            }
            __syncthreads();   // drain vmcnt: slot data at L3 before the flag
            if (tid == 0)
                astu(xfl + ((size_t)r * 4 + (tt & 3)) * FSTR, (unsigned)(tt + 1));
        }
    }
}

extern "C" void kernel_launch(void* const* d_in, const int* in_sizes, int n_in,
                              void* d_out, int out_size, void* d_ws, size_t ws_size,
                              hipStream_t stream)
{
    const float* x    = (const float*)d_in[0];
    const float* w_ih = (const float*)d_in[1];
    const float* b_ih = (const float*)d_in[2];
    const float* w_hh = (const float*)d_in[3];
    const float* b_hh = (const float*)d_in[4];
    float* out = (float*)d_out;

    const size_t gx_bytes = (size_t)4 * GX_SLOT * sizeof(float);      // 8 MB
    const size_t hb_bytes = (size_t)4 * 2 * 16384 * sizeof(unsigned); // 512 KB
    const size_t fl_bytes = (size_t)128 * FSTR * sizeof(unsigned);    // 8 KB each
    const size_t total    = gx_bytes + hb_bytes + 2 * fl_bytes;
    if (ws_size < total) return;

    char* p = (char*)d_ws;
    float*    gxr  = (float*)p;      p += gx_bytes;
    unsigned* hbuf = (unsigned*)p;   p += hb_bytes;
    unsigned* l3f  = (unsigned*)p;   p += fl_bytes;
    unsigned* xfl  = (unsigned*)p;

    // zero EVERYTHING each call: epochs restart at 0; no stale/poison data
    hipMemsetAsync(d_ws, 0, total, stream);

    void* args[] = { (void*)&x, (void*)&w_ih, (void*)&b_ih, (void*)&w_hh,
                     (void*)&b_hh, (void*)&out, (void*)&gxr, (void*)&hbuf,
                     (void*)&l3f, (void*)&xfl };
    hipError_t err = hipLaunchCooperativeKernel((const void*)lstm_main,
                                                dim3(256), dim3(512),
                                                args, 0, stream);
    if (err != hipSuccess) {
        // LDS (~83 KB) forces 1 block/CU; 256 blocks co-reside on 256 CUs
        lstm_main<<<dim3(256), dim3(512), 0, stream>>>(x, w_ih, b_ih, w_hh, b_hh,
                                                       out, gxr, hbuf, l3f, xfl);
    }
}

// Round 10
// 3943.757 us; speedup vs baseline: 2.4489x; 1.1375x over previous
//
#include <hip/hip_runtime.h>
#include <hip/hip_bf16.h>

// LSTM forward, T=512 B=128 D=1024 H=1024, fp32 in/out, bf16 MFMA compute.
//
// Round 10: de-amplify h reads via XCD-L2 sharing + bf16 gx transport.
//  - h ring depth 32 (slot = t&31): consumers use PLAIN CACHED 16B loads;
//    first toucher per XCD misses to L3, peers hit L2 (was: every consumer
//    sc1-read the same 64KB from L3 -> 8 MB/step EA traffic).
//    Freshness guaranteed by an agent acquire fence (buffer_inv) once per
//    32 steps per block (synchronized at t%32==0) -- slot addresses are
//    only reused after 32 steps, and all reads happen post-flag-poll.
//    Publish stays sc1 (the R6/R7 plain-store bug is NOT reintroduced).
//  - gx ring transported as bf16 (u64 = 4 values): halves bytes + 8B-atomic
//    transaction count of the biggest write term.
//  - ws-adaptive: if ws < full need, fall back to depth-2 ring + sc1 A-fill
//    (exact R9 transport) -- passes either way, FETCH_SIZE disambiguates.

#define NT 512
#define NB 128
#define ND 1024
#define NH 1024
#define FSTR 16                 // u32 per flag slot (64 B)
#define GUARD_STEP (1 << 17)
#define GUARD_BOOT (1 << 22)

typedef __attribute__((ext_vector_type(8))) __bf16 bf16x8;
typedef __attribute__((ext_vector_type(4))) float  f32x4;
typedef __attribute__((ext_vector_type(2))) unsigned long long ullx2;
typedef unsigned long long u64;

__device__ __forceinline__ float sigm(float x) { return 1.0f / (1.0f + __expf(-x)); }
__device__ __forceinline__ float tanh_(float x) {
    x = fminf(15.0f, fmaxf(-15.0f, x));
    float e = __expf(-2.0f * x);
    return (1.0f - e) / (1.0f + e);
}
__device__ __forceinline__ bf16x8 cvt8v(float4 f0, float4 f1) {
    bf16x8 v;
    v[0] = (__bf16)f0.x; v[1] = (__bf16)f0.y; v[2] = (__bf16)f0.z; v[3] = (__bf16)f0.w;
    v[4] = (__bf16)f1.x; v[5] = (__bf16)f1.y; v[6] = (__bf16)f1.z; v[7] = (__bf16)f1.w;
    return v;
}
__device__ __forceinline__ bf16x8 cvt8(const float* p) {
    return cvt8v(*(const float4*)p, *(const float4*)(p + 4));
}
__device__ __forceinline__ u64 ald(const u64* p) {
    return __hip_atomic_load(p, __ATOMIC_RELAXED, __HIP_MEMORY_SCOPE_AGENT);
}
__device__ __forceinline__ void ast(u64* p, u64 v) {
    __hip_atomic_store(p, v, __ATOMIC_RELAXED, __HIP_MEMORY_SCOPE_AGENT);
}
__device__ __forceinline__ unsigned aldu(const unsigned* p) {
    return __hip_atomic_load(p, __ATOMIC_RELAXED, __HIP_MEMORY_SCOPE_AGENT);
}
__device__ __forceinline__ void astu(unsigned* p, unsigned v) {
    __hip_atomic_store(p, v, __ATOMIC_RELAXED, __HIP_MEMORY_SCOPE_AGENT);
}
__device__ __forceinline__ float b2f(unsigned bits16) {
    return __builtin_bit_cast(float, bits16 << 16);
}
__device__ __forceinline__ u64 pack4(f32x4 v) {
    const unsigned short h0 = __builtin_bit_cast(unsigned short, (__bf16)v[0]);
    const unsigned short h1 = __builtin_bit_cast(unsigned short, (__bf16)v[1]);
    const unsigned short h2 = __builtin_bit_cast(unsigned short, (__bf16)v[2]);
    const unsigned short h3 = __builtin_bit_cast(unsigned short, (__bf16)v[3]);
    return (u64)h0 | ((u64)h1 << 16) | ((u64)h2 << 32) | ((u64)h3 << 48);
}

__global__ void __launch_bounds__(512, 2)
lstm_main(const float* __restrict__ x, const float* __restrict__ w_ih,
          const float* __restrict__ b_ih, const float* __restrict__ w_hh,
          const float* __restrict__ b_hh, float* __restrict__ out,
          u64* __restrict__ gxr,          // [4 slot][32 xblk][128 wcol][32 u64] bf16x4
          unsigned* __restrict__ hbuf,    // [depth][4 grp][128 k8][32 row][8 bf16]
          unsigned* __restrict__ l3f,     // [4 grp][32 blk] epoch (L3)
          unsigned* __restrict__ xfl,     // [32 xblk][4 slot] epoch (L3)
          int hmask, int cached)
{
    __shared__ uint4 ldsA[4096];          // 64 KB: [k8 128][row 32] bf16x8
    __shared__ float scr[8][32][17];      // per-wave gate exchange

    const int tid  = threadIdx.x;
    const int lane = tid & 63;
    const int wid  = tid >> 6;
    const int bid  = blockIdx.x;
    const int c = lane & 15, kslot = lane >> 4;

    if (bid < 128) {
        // ================= H engine (recurrence) =================
        const int g = bid >> 5, blk = bid & 31;

        bf16x8 wreg[32];
        {
            const size_t grow = (size_t)(c >> 2) * NH + blk * 32 + 4 * wid + (c & 3);
            const float* wp = w_hh + grow * NH + kslot * 8;
            #pragma unroll
            for (int kk = 0; kk < 32; ++kk) wreg[kk] = cvt8(wp + kk * 32);
        }
        const int row_l = lane >> 1;
        const int jjo   = (lane & 1) * 2;
        const int j0    = blk * 32 + 4 * wid + jjo;
        float bias[4][2];
        #pragma unroll
        for (int gg = 0; gg < 4; ++gg)
            #pragma unroll
            for (int u = 0; u < 2; ++u)
                bias[gg][u] = b_ih[gg * NH + j0 + u] + b_hh[gg * NH + j0 + u];
        float cst[2] = {0.f, 0.f};

        unsigned* postl3 = l3f + ((size_t)g * 32 + blk) * FSTR;

        f32x4 gxc0, gxc1;
        // gx load: 2 u64 of 4 bf16 rows each (rows 32g+4*kslot+.., +16)
        #define GXLOAD(sl) do {                                                      \
            const u64* gp_ = gxr + (((size_t)(sl)) * 32 + blk) * 4096                \
                             + (size_t)(wid * 16 + c) * 32 + 8 * g;                  \
            const u64 q0_ = ald(gp_ + kslot);                                        \
            const u64 q1_ = ald(gp_ + 4 + kslot);                                    \
            gxc0[0] = b2f((unsigned)q0_ & 0xffffu);                                  \
            gxc0[1] = b2f(((unsigned)q0_) >> 16);                                    \
            gxc0[2] = b2f((unsigned)(q0_ >> 32) & 0xffffu);                          \
            gxc0[3] = b2f((unsigned)(q0_ >> 48));                                    \
            gxc1[0] = b2f((unsigned)q1_ & 0xffffu);                                  \
            gxc1[1] = b2f(((unsigned)q1_) >> 16);                                    \
            gxc1[2] = b2f((unsigned)(q1_ >> 32) & 0xffffu);                          \
            gxc1[3] = b2f((unsigned)(q1_ >> 48));                                    \
        } while (0)

        {   // prologue: wait for gx[0]
            const unsigned* xfp0 = xfl + ((size_t)blk * 4 + 0) * FSTR;
            int gu = 0;
            while (aldu(xfp0) < 1u) {
                __builtin_amdgcn_s_sleep(8);
                if (++gu > GUARD_BOOT) break;
            }
            GXLOAD(0);
        }

        for (int t = 0; t < NT; ++t) {
            // periodic agent acquire (buffer_inv): guarantees no h-slot line
            // older than 32 steps survives in this XCD's L2 / CU's L1.
            if (cached && (t & 31) == 0) {
                if (tid < 64) __builtin_amdgcn_fence(__ATOMIC_ACQUIRE, "agent");
                __syncthreads();
            }
            if (t) {
                if (tid < 32) {   // poll my group's 32 producer epochs (sc1)
                    const unsigned* f = l3f + ((size_t)g * 32 + tid) * FSTR;
                    int gu = 0;
                    while (aldu(f) < (unsigned)t) {
                        __builtin_amdgcn_s_sleep(2);
                        if (++gu > GUARD_STEP) break;
                    }
                }
                __syncthreads();
                // A-fill: 64 KB h_{t-1} tile -> LDS
                const size_t hbase = ((size_t)((t - 1) & hmask) * 4 + g) * 16384;
                if (cached) {
                    // plain cached 16B loads: L2-shared across same-XCD peers
                    const uint4* s4 = (const uint4*)(const void*)(hbuf + hbase);
                    uint4 stc[8];
                    #pragma unroll
                    for (int i = 0; i < 8; ++i) stc[i] = s4[i * 512 + tid];
                    #pragma unroll
                    for (int i = 0; i < 8; ++i) ldsA[i * 512 + tid] = stc[i];
                } else {
                    // sc1 staged loads (R9 transport)
                    const u64* s8 = (const u64*)(const void*)(hbuf + hbase);
                    u64 st[16];
                    #pragma unroll
                    for (int i = 0; i < 8; ++i) {
                        const size_t q = (size_t)(i * 512 + tid) * 2;
                        st[2 * i]     = ald(s8 + q);
                        st[2 * i + 1] = ald(s8 + q + 1);
                    }
                    #pragma unroll
                    for (int i = 0; i < 8; ++i) {
                        ullx2 tq; tq[0] = st[2 * i]; tq[1] = st[2 * i + 1];
                        ldsA[i * 512 + tid] = __builtin_bit_cast(uint4, tq);
                    }
                }
            }
            // early epoch sample for gx[t+1]
            const unsigned* xfp = xfl + ((size_t)blk * 4 + ((t + 1) & 3)) * FSTR;
            unsigned xfNext = 0xffffffffu;
            if (t + 1 < NT) xfNext = aldu(xfp);
            __syncthreads();

            f32x4 acc0, acc1;
            if (t) {
                f32x4 a0a = gxc0, a1a = gxc1;
                f32x4 a0b = {0,0,0,0}, a1b = {0,0,0,0};
                #pragma unroll
                for (int kk = 0; kk < 32; ++kk) {
                    const bf16x8 a0 = __builtin_bit_cast(bf16x8, ldsA[(kk*4 + kslot)*32 + c]);
                    const bf16x8 a1 = __builtin_bit_cast(bf16x8, ldsA[(kk*4 + kslot)*32 + 16 + c]);
                    if (kk & 1) {
                        a0b = __builtin_amdgcn_mfma_f32_16x16x32_bf16(a0, wreg[kk], a0b, 0,0,0);
                        a1b = __builtin_amdgcn_mfma_f32_16x16x32_bf16(a1, wreg[kk], a1b, 0,0,0);
                    } else {
                        a0a = __builtin_amdgcn_mfma_f32_16x16x32_bf16(a0, wreg[kk], a0a, 0,0,0);
                        a1a = __builtin_amdgcn_mfma_f32_16x16x32_bf16(a1, wreg[kk], a1a, 0,0,0);
                    }
                }
                acc0 = a0a + a0b; acc1 = a1a + a1b;
            } else {
                acc0 = gxc0; acc1 = gxc1;
            }

            // intra-wave gate exchange (C-layout: col=lane&15, row=(lane>>4)*4+r)
            #pragma unroll
            for (int r = 0; r < 4; ++r) {
                scr[wid][kslot * 4 + r][c]      = acc0[r];
                scr[wid][16 + kslot * 4 + r][c] = acc1[r];
            }
            // cell update: lane finishes cells (row_l, j0) and (row_l, j0+1)
            float hv[2];
            #pragma unroll
            for (int u = 0; u < 2; ++u) {
                const float iv = sigm (scr[wid][row_l][ 0 + jjo + u] + bias[0][u]);
                const float fv = sigm (scr[wid][row_l][ 4 + jjo + u] + bias[1][u]);
                const float gv = tanh_(scr[wid][row_l][ 8 + jjo + u] + bias[2][u]);
                const float ov = sigm (scr[wid][row_l][12 + jjo + u] + bias[3][u]);
                const float cc = fv * cst[u] + iv * gv;
                cst[u] = cc;
                hv[u] = ov * tanh_(cc);
            }

            // publish h_t (tiled bf16, sc1 into ring slot t&hmask) -> drain -> flag
            {
                const unsigned short u0 = __builtin_bit_cast(unsigned short, (__bf16)hv[0]);
                const unsigned short u1 = __builtin_bit_cast(unsigned short, (__bf16)hv[1]);
                const unsigned pack = (unsigned)u0 | ((unsigned)u1 << 16);
                const size_t hidx = ((size_t)(t & hmask) * 4 + g) * 16384
                                  + ((size_t)(j0 >> 3) * 32 + row_l) * 4 + ((j0 & 7) >> 1);
                astu(&hbuf[hidx], pack);
            }
            __syncthreads();   // vmcnt(0): h stores at L3 before the flag
            if (tid == 0) astu(postl3, (unsigned)(t + 1));

            // off-critical-path out stores (after flag post)
            {
                float2 o; o.x = hv[0]; o.y = hv[1];
                *(float2*)&out[((size_t)t * NB + 32 * g + row_l) * NH + j0] = o;
                if (t == NT - 1)
                    *(float2*)&out[(size_t)NT * NB * NH + ((size_t)32 * g + row_l) * NH + j0] = o;
            }
            // prefetch gx[t+1]
            if (t + 1 < NT) {
                int gu = 0;
                while (xfNext < (unsigned)(t + 2)) {
                    __builtin_amdgcn_s_sleep(1);
                    xfNext = aldu(xfp);
                    if (++gu > GUARD_STEP) break;
                }
                GXLOAD((t + 1) & 3);
            }
        }
        {   // c_n
            float2 cn; cn.x = cst[0]; cn.y = cst[1];
            *(float2*)&out[(size_t)NT * NB * NH + (size_t)NB * NH
                           + ((size_t)32 * g + row_l) * NH + j0] = cn;
        }
    } else {
        // ================= X engine (gx producer, runs ahead) =================
        const int e = (bid - 128) >> 5, r = bid & 31;

        bf16x8 wreg[32];
        {
            const size_t grow = (size_t)(c >> 2) * NH + r * 32 + 4 * wid + (c & 3);
            const float* wp = w_ih + grow * ND + kslot * 8;
            #pragma unroll
            for (int kk = 0; kk < 32; ++kk) wreg[kk] = cvt8(wp + kk * 32);
        }
        const int xrow = tid >> 4, seg = tid & 15;

        for (int tt = e; tt < NT; tt += 4) {
            if (tt >= 4) {
                // throttle: all 4 consumer groups must have finished step tt-4
                const unsigned* hp = l3f + ((size_t)(lane & 3) * 32 + r) * FSTR;
                int gu = 0;
                while (aldu(hp) < (unsigned)(tt - 3)) {
                    __builtin_amdgcn_s_sleep(4);
                    if (++gu > GUARD_STEP) break;
                }
            }
            __syncthreads();

            f32x4 xa0={0,0,0,0}, xa1={0,0,0,0}, xa2={0,0,0,0}, xa3={0,0,0,0};
            f32x4 xa4={0,0,0,0}, xa5={0,0,0,0}, xa6={0,0,0,0}, xa7={0,0,0,0};

            // staged x-chunk: issue all 16 float4 loads, then convert+write
            #define XCHUNK(m, A, B) {                                                \
                const float* xs = x + ((size_t)tt * NB + 32 * (m) + xrow) * ND       \
                                    + seg * 64;                                      \
                float4 xf[16];                                                       \
                _Pragma("unroll")                                                    \
                for (int i2 = 0; i2 < 8; ++i2) {                                     \
                    xf[2 * i2]     = *(const float4*)(xs + i2 * 8);                  \
                    xf[2 * i2 + 1] = *(const float4*)(xs + i2 * 8 + 4);              \
                }                                                                    \
                _Pragma("unroll")                                                    \
                for (int i2 = 0; i2 < 8; ++i2)                                       \
                    ldsA[(seg * 8 + i2) * 32 + xrow] =                               \
                        __builtin_bit_cast(uint4, cvt8v(xf[2*i2], xf[2*i2+1]));      \
                __syncthreads();                                                     \
                _Pragma("unroll")                                                    \
                for (int kk = 0; kk < 32; ++kk) {                                    \
                    const bf16x8 a0 = __builtin_bit_cast(bf16x8,                     \
                        ldsA[(kk*4 + kslot)*32 + c]);                                \
                    const bf16x8 a1 = __builtin_bit_cast(bf16x8,                     \
                        ldsA[(kk*4 + kslot)*32 + 16 + c]);                           \
                    A = __builtin_amdgcn_mfma_f32_16x16x32_bf16(a0, wreg[kk], A, 0,0,0);\
                    B = __builtin_amdgcn_mfma_f32_16x16x32_bf16(a1, wreg[kk], B, 0,0,0);\
                }                                                                    \
                __syncthreads(); }

            XCHUNK(0, xa0, xa1)
            XCHUNK(1, xa2, xa3)
            XCHUNK(2, xa4, xa5)
            XCHUNK(3, xa6, xa7)

            {   // store gx[tt] slot as bf16 (sc1 -> L3): u64 = 4 consecutive rows
                u64* gp = gxr + (((size_t)(tt & 3)) * 32 + r) * 4096
                          + (size_t)(wid * 16 + c) * 32;
                ast(gp + kslot,          pack4(xa0));   // m0 rows kslot*4+0..3
                ast(gp + 4 + kslot,      pack4(xa1));   // m0 rows 16+kslot*4+..
                ast(gp + 8 + kslot,      pack4(xa2));   // m1
                ast(gp + 12 + kslot,     pack4(xa3));
                ast(gp + 16 + kslot,     pack4(xa4));   // m2
                ast(gp + 20 + kslot,     pack4(xa5));
                ast(gp + 24 + kslot,     pack4(xa6));   // m3
                ast(gp + 28 + kslot,     pack4(xa7));
            }
            __syncthreads();   // drain vmcnt: slot data at L3 before the flag
            if (tid == 0)
                astu(xfl + ((size_t)r * 4 + (tt & 3)) * FSTR, (unsigned)(tt + 1));
        }
    }
}

extern "C" void kernel_launch(void* const* d_in, const int* in_sizes, int n_in,
                              void* d_out, int out_size, void* d_ws, size_t ws_size,
                              hipStream_t stream)
{
    const float* x    = (const float*)d_in[0];
    const float* w_ih = (const float*)d_in[1];
    const float* b_ih = (const float*)d_in[2];
    const float* w_hh = (const float*)d_in[3];
    const float* b_hh = (const float*)d_in[4];
    float* out = (float*)d_out;

    const size_t gx_bytes = (size_t)4 * 32 * 4096 * sizeof(u64);      // 4 MB (bf16)
    const size_t fl_bytes = (size_t)128 * FSTR * sizeof(unsigned);    // 8 KB each
    const size_t hb_full  = (size_t)32 * 4 * 16384 * sizeof(unsigned);// 8 MB ring
    const size_t hb_min   = (size_t)2  * 4 * 16384 * sizeof(unsigned);// 512 KB ring

    int hmask, cached;
    size_t hb_bytes;
    if (ws_size >= gx_bytes + hb_full + 2 * fl_bytes) {
        hmask = 31; cached = 1; hb_bytes = hb_full;       // tier 1: L2-shared
    } else if (ws_size >= gx_bytes + hb_min + 2 * fl_bytes) {
        hmask = 1;  cached = 0; hb_bytes = hb_min;        // tier 2: R9 transport
    } else {
        return;
    }
    const size_t total = gx_bytes + hb_bytes + 2 * fl_bytes;

    char* p = (char*)d_ws;
    u64*      gxr  = (u64*)p;        p += gx_bytes;
    unsigned* hbuf = (unsigned*)p;   p += hb_bytes;
    unsigned* l3f  = (unsigned*)p;   p += fl_bytes;
    unsigned* xfl  = (unsigned*)p;

    // zero everything used each call: epochs restart at 0; no stale data
    hipMemsetAsync(d_ws, 0, total, stream);

    void* args[] = { (void*)&x, (void*)&w_ih, (void*)&b_ih, (void*)&w_hh,
                     (void*)&b_hh, (void*)&out, (void*)&gxr, (void*)&hbuf,
                     (void*)&l3f, (void*)&xfl, (void*)&hmask, (void*)&cached };
    hipError_t err = hipLaunchCooperativeKernel((const void*)lstm_main,
                                                dim3(256), dim3(512),
                                                args, 0, stream);
    if (err != hipSuccess) {
        // LDS (~83 KB) forces 1 block/CU; 256 blocks co-reside on 256 CUs
        lstm_main<<<dim3(256), dim3(512), 0, stream>>>(x, w_ih, b_ih, w_hh, b_hh,
                                                       out, gxr, hbuf, l3f, xfl,
                                                       hmask, cached);
    }
}